// Round 1
// 122.256 us; speedup vs baseline: 1.0242x; 1.0242x over previous
//
#include <hip/hip_runtime.h>
#include <math.h>

#define B_TOT 2048
#define R_TOT 512
#define D_TOT 256
#define LOG2E 1.4426950408889634f
#define SCALE_C 2.220446049250313e-16f   // 2^-52 exact

typedef float vf4 __attribute__((ext_vector_type(4)));
typedef float vf2 __attribute__((ext_vector_type(2)));

// gated = (1 + m1*e)/(1 + e),  e = exp2(A*x + Bc)
// A = -log2e*kappa*tanh(sign), Bc = -A*th, m1 = 1 - sigmoid(mask)
// Param planes: ppA[r*256+d], ppB[r*256+d], ppM[r*256+d].
// ppM carries 2^-52 folded at d%8==0 so each 8-d rcp group's num/den both
// carry the same scale -> ratio exact.
// Also zeroes y (blocks 0..7) so the separate memset dispatch is dropped.

__global__ void prep_kernel(const float* __restrict__ th,
                            const float* __restrict__ sp,
                            const float* __restrict__ ml,
                            const float* __restrict__ lk,
                            float* __restrict__ pp,
                            float* __restrict__ y) {
    int idx = blockIdx.x * 256 + threadIdx.x;   // r*256 + d
    if (blockIdx.x < (B_TOT / 256)) y[idx] = 0.0f;   // idx < 2048 here
    if (idx >= R_TOT * D_TOT) return;
    float kmul = -LOG2E * __builtin_amdgcn_exp2f(lk[0] * LOG2E);
    float u  = sp[idx];
    float eu = __builtin_amdgcn_exp2f(2.0f * LOG2E * u);
    float t  = 1.0f - 2.0f * __builtin_amdgcn_rcpf(eu + 1.0f);
    float A  = kmul * t;
    float Bc = -A * th[idx];
    float em = __builtin_amdgcn_exp2f(LOG2E * ml[idx]);
    float m1 = __builtin_amdgcn_rcpf(1.0f + em);
    int d = idx & 255;
    pp[idx]                       = A;
    pp[R_TOT * D_TOT + idx]       = Bc;
    pp[2 * R_TOT * D_TOT + idx]   = m1 * (((d & 7) == 0) ? SCALE_C : 1.0f);
}

// lane^1 swap via DPP quad_perm [1,0,3,2] = 0xB1 (pure VALU, no LDS)
static __device__ __forceinline__ float pair_swap(float v) {
    int i = __builtin_amdgcn_mov_dpp(__float_as_int(v), 0xB1, 0xF, 0xF, true);
    return __int_as_float(i);
}

// ---------------------------------------------------------------------------
// Main: WG = 256 = 4 waves. wave -> 1 rule; WG -> 4 rules x 16 batches.
// lane l owns d = 4l..4l+3; params live in 12 VGPRs for the whole kernel.
// Per 2 batches: two coalesced dwordx4 x-loads, packed math, 8 exp2, ONE rcp
// serving both 8-d pair ratios (inv of the product of the two denominators).
// Ratios streamed to LDS per-iteration (no 16-deep register array ->
// VGPR <= 64 -> 8 blocks/CU with __launch_bounds__(256,8)).
// grid = (512/4 rules, 2048/16 batches) = 128 x 128.
// ---------------------------------------------------------------------------
__global__ __launch_bounds__(256, 8) void main_kernel(
        const float* __restrict__ x,       // [B_TOT][D_TOT]
        const float* __restrict__ pp,      // 3 planes of [R_TOT][D_TOT]
        const float* __restrict__ head_w,  // [R_TOT]
        const float* __restrict__ head_b,  // [1]
        float*       __restrict__ y) {     // [B_TOT]
    __shared__ float rbuf[4][16][36];      // pad 36: 16B-aligned, <=2-way banks
    __shared__ float wz[4][16];

    const int tid  = threadIdx.x;
    const int lane = tid & 63;
    const int wave = tid >> 6;
    const int r0   = (blockIdx.x << 2) + wave;   // this wave's rule
    const int b0   = blockIdx.y << 4;            // 16 batches

    // ---- params: one coalesced vf4 load per plane, held in VGPRs ----
    const vf4* pA = (const vf4*)pp                         + r0 * 64 + lane;
    const vf4* pB = (const vf4*)(pp + R_TOT * D_TOT)       + r0 * 64 + lane;
    const vf4* pM = (const vf4*)(pp + 2 * R_TOT * D_TOT)   + r0 * 64 + lane;
    vf4 A  = *pA;
    vf4 Bc = *pB;
    vf4 Ms = *pM;
    const float kx = (lane & 1) ? 1.0f : SCALE_C;
    const vf4 K = {kx, 1.0f, 1.0f, 1.0f};

    const vf4* xv = (const vf4*)x + (size_t)b0 * 64 + lane;

    // column pointer for this lane-pair's ratio slot (written by even lane)
    float* rcol = &rbuf[wave][0][lane >> 1];
    const bool wr = !(lane & 1);

    #pragma unroll
    for (int bp = 0; bp < 8; bp++) {
        vf4 x0 = xv[(2 * bp) * 64];          // coalesced 1 KB/wave, L1/L2 hit
        vf4 x1 = xv[(2 * bp + 1) * 64];
        vf4 t0 = A * x0 + Bc;                // v_pk_fma_f32
        vf4 t1 = A * x1 + Bc;
        vf4 e0, e1;
        e0.x = __builtin_amdgcn_exp2f(t0.x);
        e0.y = __builtin_amdgcn_exp2f(t0.y);
        e0.z = __builtin_amdgcn_exp2f(t0.z);
        e0.w = __builtin_amdgcn_exp2f(t0.w);
        e1.x = __builtin_amdgcn_exp2f(t1.x);
        e1.y = __builtin_amdgcn_exp2f(t1.y);
        e1.z = __builtin_amdgcn_exp2f(t1.z);
        e1.w = __builtin_amdgcn_exp2f(t1.w);
        vf4 n0 = Ms * e0 + K;                // scaled numerator factors
        vf4 d0 = e0 * K + K;                 // scaled denominator factors
        vf4 n1 = Ms * e1 + K;
        vf4 d1 = e1 * K + K;
        vf2 hn0 = n0.lo * n0.hi;
        vf2 hd0 = d0.lo * d0.hi;
        vf2 hn1 = n1.lo * n1.hi;
        vf2 hd1 = d1.lo * d1.hi;
        float np0 = hn0.x * hn0.y;           // lane's 4-d num product
        float dp0 = hd0.x * hd0.y;
        float np1 = hn1.x * hn1.y;
        float dp1 = hd1.x * hd1.y;
        float np8_0 = np0 * pair_swap(np0);  // 8-d group (lane pair)
        float dp8_0 = dp0 * pair_swap(dp0);
        float np8_1 = np1 * pair_swap(np1);
        float dp8_1 = dp1 * pair_swap(dp1);
        // one rcp serves both batches: r_b = np8_b / dp8_b
        // dp8 in [2^-52, ~2^80] with this data -> product stays normal f32
        float inv = __builtin_amdgcn_rcpf(dp8_0 * dp8_1);
        float ra  = np8_0 * (dp8_1 * inv);   // in [0.6^8, 1] (scaled exact)
        float rb  = np8_1 * (dp8_0 * inv);
        if (wr) {
            rcol[(2 * bp) * 36]     = ra;    // stream to LDS: no r8[16] regs
            rcol[(2 * bp + 1) * 36] = rb;
        }
    }

    // ---- end-phase: per-batch product over the 32 ratio columns ----
    __syncthreads();

    if (lane < 16) {
        const float* rb2 = &rbuf[wave][lane][0];
        vf4 a0 = *(const vf4*)(rb2)      * *(const vf4*)(rb2 + 4);
        vf4 a1 = *(const vf4*)(rb2 + 8)  * *(const vf4*)(rb2 + 12);
        vf4 a2 = *(const vf4*)(rb2 + 16) * *(const vf4*)(rb2 + 20);
        vf4 a3 = *(const vf4*)(rb2 + 24) * *(const vf4*)(rb2 + 28);
        vf4 m  = (a0 * a1) * (a2 * a3);
        vf2 h  = m.lo * m.hi;
        float z = h.x * h.y;                 // z(b, r0)
        wz[wave][lane] = head_w[r0] * z;
    }
    __syncthreads();

    if (wave == 0 && lane < 16) {
        float s = wz[0][lane] + wz[1][lane] + wz[2][lane] + wz[3][lane];
        if (blockIdx.x == 0) s += head_b[0];   // bias exactly once per batch
        atomicAdd(&y[b0 + lane], s);
    }
}

extern "C" void kernel_launch(void* const* d_in, const int* in_sizes, int n_in,
                              void* d_out, int out_size, void* d_ws, size_t ws_size,
                              hipStream_t stream) {
    const float* x  = (const float*)d_in[0];
    const float* th = (const float*)d_in[1];
    const float* sp = (const float*)d_in[2];
    const float* ml = (const float*)d_in[3];
    const float* lk = (const float*)d_in[4];
    const float* hw = (const float*)d_in[5];
    const float* hb = (const float*)d_in[6];
    float* y = (float*)d_out;

    float* pp = (float*)d_ws;   // 3 * 512 * 256 floats = 1.5 MB

    prep_kernel<<<R_TOT, 256, 0, stream>>>(th, sp, ml, lk, pp, y);
    dim3 grid(R_TOT / 4, B_TOT / 16, 1);
    main_kernel<<<grid, 256, 0, stream>>>(x, pp, hw, hb, y);
}

// Round 2
// 117.067 us; speedup vs baseline: 1.0696x; 1.0443x over previous
//
#include <hip/hip_runtime.h>
#include <math.h>

#define B_TOT 2048
#define R_TOT 512
#define D_TOT 256
#define LOG2E 1.4426950408889634f
#define SCALE_C 2.220446049250313e-16f   // 2^-52 exact

typedef float vf4 __attribute__((ext_vector_type(4)));
typedef float vf2 __attribute__((ext_vector_type(2)));

// gated = (1 + m1*e)/(1 + e),  e = exp2(A*x + Bc)
// A = -log2e*kappa*tanh(sign), Bc = -A*th, m1 = 1 - sigmoid(mask)
// Param planes: ppA[r*256+d], ppB[r*256+d], ppM[r*256+d].
// ppM carries 2^-52 folded at d%8==0 so each 8-d rcp group's num/den both
// carry the same scale -> ratio exact.
// Also zeroes y (blocks 0..7) so the separate memset dispatch is dropped.

__global__ void prep_kernel(const float* __restrict__ th,
                            const float* __restrict__ sp,
                            const float* __restrict__ ml,
                            const float* __restrict__ lk,
                            float* __restrict__ pp,
                            float* __restrict__ y) {
    int idx = blockIdx.x * 256 + threadIdx.x;   // r*256 + d
    if (blockIdx.x < (B_TOT / 256)) y[idx] = 0.0f;   // idx < 2048 here
    if (idx >= R_TOT * D_TOT) return;
    float kmul = -LOG2E * __builtin_amdgcn_exp2f(lk[0] * LOG2E);
    float u  = sp[idx];
    float eu = __builtin_amdgcn_exp2f(2.0f * LOG2E * u);
    float t  = 1.0f - 2.0f * __builtin_amdgcn_rcpf(eu + 1.0f);
    float A  = kmul * t;
    float Bc = -A * th[idx];
    float em = __builtin_amdgcn_exp2f(LOG2E * ml[idx]);
    float m1 = __builtin_amdgcn_rcpf(1.0f + em);
    int d = idx & 255;
    pp[idx]                       = A;
    pp[R_TOT * D_TOT + idx]       = Bc;
    pp[2 * R_TOT * D_TOT + idx]   = m1 * (((d & 7) == 0) ? SCALE_C : 1.0f);
}

// ---------------------------------------------------------------------------
// Main: WG = 256 = 4 waves. wave -> 1 rule; WG -> 4 rules x 16 batches.
// NEW layout: lane l owns the FULL 8-d group d = 8*(l&31)..+7; the lane
// halves (p = l>>5) cover two batch rows per step. This removes all DPP
// pair-swap ops and all cross-lane stitching: the 8-way num/den products
// are pure in-lane trees. One rcp serves 2 batches (cross-multiply, same
// trick/numerics as before). Params stay in 24 VGPRs for the whole kernel.
// Per q (4 batches, 16 elems/lane): 4 coalesced dwordx4 x-loads, 16 exp2,
// ~48 VALU, 1 rcp, 2 conflict-free ds_writes.
// grid = (512/4 rules, 2048/16 batches) = 128 x 128.
// ---------------------------------------------------------------------------
__global__ __launch_bounds__(256, 4) void main_kernel(
        const float* __restrict__ x,       // [B_TOT][D_TOT]
        const float* __restrict__ pp,      // 3 planes of [R_TOT][D_TOT]
        const float* __restrict__ head_w,  // [R_TOT]
        const float* __restrict__ head_b,  // [1]
        float*       __restrict__ y) {     // [B_TOT]
    __shared__ float rbuf[4][16][36];      // pad 36: 16B-aligned, 2-way banks
    __shared__ float wz[4][16];

    const int tid  = threadIdx.x;
    const int lane = tid & 63;
    const int wave = tid >> 6;
    const int col  = lane & 31;            // which 8-d group
    const int p    = lane >> 5;            // batch parity within row pair
    const int r0   = (blockIdx.x << 2) + wave;   // this wave's rule
    const int b0   = blockIdx.y << 4;            // 16 batches

    // ---- params: 8 d's per lane = two vf4 per plane, held in VGPRs ----
    const float* ppr = pp + r0 * D_TOT + (col << 3);
    vf4 A0  = *(const vf4*)(ppr);
    vf4 A1  = *(const vf4*)(ppr + 4);
    vf4 Bc0 = *(const vf4*)(ppr + R_TOT * D_TOT);
    vf4 Bc1 = *(const vf4*)(ppr + R_TOT * D_TOT + 4);
    vf4 M0  = *(const vf4*)(ppr + 2 * R_TOT * D_TOT);     // .x carries 2^-52
    vf4 M1  = *(const vf4*)(ppr + 2 * R_TOT * D_TOT + 4);
    const vf4 Klo = {SCALE_C, 1.0f, 1.0f, 1.0f};

    const float* xb = x + (size_t)(b0 + p) * D_TOT + (col << 3);

    #pragma unroll
    for (int q = 0; q < 4; q++) {
        // batch rows 4q+p ("A") and 4q+2+p ("C")
        const float* xq = xb + q * (4 * D_TOT);
        vf4 xa0 = *(const vf4*)(xq);
        vf4 xa1 = *(const vf4*)(xq + 4);
        vf4 xc0 = *(const vf4*)(xq + 2 * D_TOT);
        vf4 xc1 = *(const vf4*)(xq + 2 * D_TOT + 4);

        vf4 ta0 = A0 * xa0 + Bc0;          // v_pk_fma_f32
        vf4 ta1 = A1 * xa1 + Bc1;
        vf4 tc0 = A0 * xc0 + Bc0;
        vf4 tc1 = A1 * xc1 + Bc1;

        vf4 ea0, ea1, ec0, ec1;
        ea0.x = __builtin_amdgcn_exp2f(ta0.x);
        ea0.y = __builtin_amdgcn_exp2f(ta0.y);
        ea0.z = __builtin_amdgcn_exp2f(ta0.z);
        ea0.w = __builtin_amdgcn_exp2f(ta0.w);
        ea1.x = __builtin_amdgcn_exp2f(ta1.x);
        ea1.y = __builtin_amdgcn_exp2f(ta1.y);
        ea1.z = __builtin_amdgcn_exp2f(ta1.z);
        ea1.w = __builtin_amdgcn_exp2f(ta1.w);
        ec0.x = __builtin_amdgcn_exp2f(tc0.x);
        ec0.y = __builtin_amdgcn_exp2f(tc0.y);
        ec0.z = __builtin_amdgcn_exp2f(tc0.z);
        ec0.w = __builtin_amdgcn_exp2f(tc0.w);
        ec1.x = __builtin_amdgcn_exp2f(tc1.x);
        ec1.y = __builtin_amdgcn_exp2f(tc1.y);
        ec1.z = __builtin_amdgcn_exp2f(tc1.z);
        ec1.w = __builtin_amdgcn_exp2f(tc1.w);

        // scaled numerator / denominator factors (scale on first elem only)
        vf4 na0 = M0 * ea0 + Klo;
        vf4 na1 = M1 * ea1 + 1.0f;
        vf4 da0 = ea0 * Klo + Klo;
        vf4 da1 = ea1 + 1.0f;
        vf4 nc0 = M0 * ec0 + Klo;
        vf4 nc1 = M1 * ec1 + 1.0f;
        vf4 dc0 = ec0 * Klo + Klo;
        vf4 dc1 = ec1 + 1.0f;

        // in-lane 8-way product trees
        vf4 qn_a = na0 * na1;
        vf4 qd_a = da0 * da1;
        vf4 qn_c = nc0 * nc1;
        vf4 qd_c = dc0 * dc1;
        vf2 hn_a = qn_a.lo * qn_a.hi;
        vf2 hd_a = qd_a.lo * qd_a.hi;
        vf2 hn_c = qn_c.lo * qn_c.hi;
        vf2 hd_c = qd_c.lo * qd_c.hi;
        float npA = hn_a.x * hn_a.y;
        float dpA = hd_a.x * hd_a.y;
        float npC = hn_c.x * hn_c.y;
        float dpC = hd_c.x * hd_c.y;

        // one rcp serves both batches: r_b = np_b / dp_b
        // dp in [2^-52, ~2^-15] typical with this data -> product normal f32
        float inv = __builtin_amdgcn_rcpf(dpA * dpC);
        float rA  = npA * (dpC * inv);
        float rC  = npC * (dpA * inv);
        rbuf[wave][4 * q + p][col]     = rA;
        rbuf[wave][4 * q + 2 + p][col] = rC;
    }

    // ---- end-phase: per-batch product over the 32 ratio columns ----
    __syncthreads();

    if (lane < 16) {
        const float* rb2 = &rbuf[wave][lane][0];
        vf4 a0 = *(const vf4*)(rb2)      * *(const vf4*)(rb2 + 4);
        vf4 a1 = *(const vf4*)(rb2 + 8)  * *(const vf4*)(rb2 + 12);
        vf4 a2 = *(const vf4*)(rb2 + 16) * *(const vf4*)(rb2 + 20);
        vf4 a3 = *(const vf4*)(rb2 + 24) * *(const vf4*)(rb2 + 28);
        vf4 m  = (a0 * a1) * (a2 * a3);
        vf2 h  = m.lo * m.hi;
        float z = h.x * h.y;                 // z(b, r0)
        wz[wave][lane] = head_w[r0] * z;
    }
    __syncthreads();

    if (wave == 0 && lane < 16) {
        float s = wz[0][lane] + wz[1][lane] + wz[2][lane] + wz[3][lane];
        if (blockIdx.x == 0) s += head_b[0];   // bias exactly once per batch
        atomicAdd(&y[b0 + lane], s);
    }
}

extern "C" void kernel_launch(void* const* d_in, const int* in_sizes, int n_in,
                              void* d_out, int out_size, void* d_ws, size_t ws_size,
                              hipStream_t stream) {
    const float* x  = (const float*)d_in[0];
    const float* th = (const float*)d_in[1];
    const float* sp = (const float*)d_in[2];
    const float* ml = (const float*)d_in[3];
    const float* lk = (const float*)d_in[4];
    const float* hw = (const float*)d_in[5];
    const float* hb = (const float*)d_in[6];
    float* y = (float*)d_out;

    float* pp = (float*)d_ws;   // 3 * 512 * 256 floats = 1.5 MB

    prep_kernel<<<R_TOT, 256, 0, stream>>>(th, sp, ml, lk, pp, y);
    dim3 grid(R_TOT / 4, B_TOT / 16, 1);
    main_kernel<<<grid, 256, 0, stream>>>(x, pp, hw, hb, y);
}